// Round 8
// baseline (1873.787 us; speedup 1.0000x reference)
//
#include <hip/hip_runtime.h>
#include <math.h>

#define B_ 512
#define S_ 500
#define NQ1_ 10001
#define NQA1_ 20001
#define BS_ (B_ * S_)

typedef float v2f __attribute__((ext_vector_type(2)));
static __device__ __forceinline__ v2f pkfma(v2f a, v2f b, v2f c) {
    return __builtin_elementwise_fma(a, b, c);
}

// ---------------------------------------------------------------------------
// Fused prep: WeT, WaT, MkT, WsqT transposes + WsrP bf16-pack (j-pairs).
// WsrP[k*64 + l] = bf16(Ws[2l][k]) | bf16(Ws[2l+1][k])<<16,  k<256, l<64.
// ---------------------------------------------------------------------------
__global__ __launch_bounds__(256) void prep_kernel(
    const float* __restrict__ We, const float* __restrict__ Wa,
    const float* __restrict__ Mk, const float* __restrict__ Ws,
    float* __restrict__ WeT, float* __restrict__ WaT,
    float* __restrict__ MkT, float* __restrict__ WsqT,
    unsigned int* __restrict__ WsrP)
{
    int idx = blockIdx.x * 256 + threadIdx.x;
    if (idx < 65536) {
        int r = idx >> 8, c = idx & 255;
        WeT[c * 256 + r] = We[r * 256 + c];
        return;
    }
    idx -= 65536;
    if (idx < 65536) {
        int r = idx >> 8, c = idx & 255;
        WaT[c * 256 + r] = Wa[r * 256 + c];
        return;
    }
    idx -= 65536;
    if (idx < 16384) {
        int r = idx >> 7, c = idx & 127;
        MkT[c * 128 + r] = Mk[r * 128 + c];
        return;
    }
    idx -= 16384;
    if (idx < 16384) {
        int r = idx >> 7, c = idx & 127;
        WsqT[c * 128 + r] = Ws[r * 384 + 256 + c];
        return;
    }
    idx -= 16384;
    if (idx < 16384) {
        int k = idx >> 6, l = idx & 63;
        unsigned int b0 = __float_as_uint(Ws[(2 * l) * 384 + k]);
        unsigned int b1 = __float_as_uint(Ws[(2 * l + 1) * 384 + k]);
        WsrP[k * 64 + l] = ((b0 + 0x8000u) >> 16) | ((b1 + 0x8000u) & 0xFFFF0000u);
    }
}

// ---------------------------------------------------------------------------
// Per-q-index precompute: Wsm = softmax(q@Mk.T), Sq = q@Ws_q.T, dq = tanh(q@Wd+bd)
// ---------------------------------------------------------------------------
__global__ __launch_bounds__(64) void kq_kernel(
    const float* __restrict__ q_embed, const float* __restrict__ MkT,
    const float* __restrict__ WsqT, const float* __restrict__ Wd,
    const float* __restrict__ bdp,
    float* __restrict__ Wsm, float* __restrict__ Sq, float* __restrict__ dqv)
{
    int i0 = blockIdx.x * 8;
    int l = threadIdx.x;  // 0..63 -> j = 2l, 2l+1
    __shared__ float qlds[8][128];

#pragma unroll
    for (int r = 0; r < 8; ++r) {
        int i = i0 + r;
        v2f qv = { 0.f, 0.f };
        if (i < NQ1_) qv = *reinterpret_cast<const v2f*>(&q_embed[i * 128 + 2 * l]);
        *reinterpret_cast<v2f*>(&qlds[r][2 * l]) = qv;
    }
    __syncthreads();

    v2f lg[8], sq[8];
#pragma unroll
    for (int r = 0; r < 8; ++r) { lg[r] = (v2f){0.f, 0.f}; sq[r] = (v2f){0.f, 0.f}; }

    for (int k = 0; k < 128; ++k) {
        v2f mk = *reinterpret_cast<const v2f*>(&MkT[k * 128 + 2 * l]);
        v2f wq = *reinterpret_cast<const v2f*>(&WsqT[k * 128 + 2 * l]);
#pragma unroll
        for (int r = 0; r < 8; ++r) {
            float q = qlds[r][k];
            v2f q2 = { q, q };
            lg[r] = pkfma(q2, mk, lg[r]);
            sq[r] = pkfma(q2, wq, sq[r]);
        }
    }

    v2f wd2 = *reinterpret_cast<const v2f*>(&Wd[2 * l]);
    float bd = bdp[0];

#pragma unroll
    for (int r = 0; r < 8; ++r) {
        int i = i0 + r;
        float m = fmaxf(lg[r].x, lg[r].y);
        for (int off = 32; off; off >>= 1) m = fmaxf(m, __shfl_xor(m, off));
        float ex0 = expf(lg[r].x - m), ex1 = expf(lg[r].y - m);
        float s = ex0 + ex1;
        for (int off = 32; off; off >>= 1) s += __shfl_xor(s, off);
        float inv = 1.f / s;
        if (i < NQ1_) {
            v2f o = { ex0 * inv, ex1 * inv };
            *reinterpret_cast<v2f*>(&Wsm[i * 128 + 2 * l]) = o;
            *reinterpret_cast<v2f*>(&Sq[i * 128 + 2 * l]) = sq[r];
        }
        float dd = qlds[r][2 * l] * wd2.x + qlds[r][2 * l + 1] * wd2.y;
        for (int off = 32; off; off >>= 1) dd += __shfl_xor(dd, off);
        if (l == 0 && i < NQ1_) dqv[i] = tanhf(dd + bd);
    }
}

// ---------------------------------------------------------------------------
// Per-qa-index precompute: EA[i][d] = (sigmoid(..)_d, tanh(..)_d) interleaved.
// ---------------------------------------------------------------------------
__global__ __launch_bounds__(128) void kqa_kernel(
    const float* __restrict__ qa_embed, const float* __restrict__ WeT,
    const float* __restrict__ WaT, const float* __restrict__ be,
    const float* __restrict__ ba, float* __restrict__ EA)
{
    int i0 = blockIdx.x * 8;
    int l = threadIdx.x;  // 0..127 -> d = 2l, 2l+1
    __shared__ float qlds[8][256];

#pragma unroll
    for (int r = 0; r < 8; ++r) {
        int i = i0 + r;
        v2f qv = { 0.f, 0.f };
        if (i < NQA1_) qv = *reinterpret_cast<const v2f*>(&qa_embed[i * 256 + 2 * l]);
        *reinterpret_cast<v2f*>(&qlds[r][2 * l]) = qv;
    }
    __syncthreads();

    v2f be2 = *reinterpret_cast<const v2f*>(&be[2 * l]);
    v2f ba2 = *reinterpret_cast<const v2f*>(&ba[2 * l]);
    v2f zE[8], zA[8];
#pragma unroll
    for (int r = 0; r < 8; ++r) { zE[r] = be2; zA[r] = ba2; }

    for (int k = 0; k < 256; ++k) {
        v2f we2 = *reinterpret_cast<const v2f*>(&WeT[k * 256 + 2 * l]);
        v2f wa2 = *reinterpret_cast<const v2f*>(&WaT[k * 256 + 2 * l]);
#pragma unroll
        for (int r = 0; r < 8; ++r) {
            float q = qlds[r][k];
            v2f q2 = { q, q };
            zE[r] = pkfma(q2, we2, zE[r]);
            zA[r] = pkfma(q2, wa2, zA[r]);
        }
    }
#pragma unroll
    for (int r = 0; r < 8; ++r) {
        int i = i0 + r;
        if (i < NQA1_) {
            float4 o;
            o.x = 1.f / (1.f + expf(-zE[r].x));
            o.y = tanhf(zA[r].x);
            o.z = 1.f / (1.f + expf(-zE[r].y));
            o.w = tanhf(zA[r].y);
            *reinterpret_cast<float4*>(&EA[(size_t)(i * 256 + 2 * l) * 2]) = o;
        }
    }
}

// ---------------------------------------------------------------------------
// Recurrence v3: 5-stage pipeline, ONE barrier per step, minimal LDS traffic.
//  - Mv in 64 VGPRs (thread (h,d) owns rows h*64..h*64+63, col d).
//  - Wsr slice in 32 bf16-packed VGPRs (thread (g,l) owns k=g*32..+31, j=2l,2l+1).
//  - w row read via SCALAR loads (block-uniform address forced by
//    readfirstlane) -> s_load_dwordx4 into SGPRs, no LDS staging.
//  - LDS only for rbuf1/rfull/zpart/sred/dqring (~14 KB static).
// NOTE: plain __launch_bounds__(512) only — (512,4) and waves_per_eu(4) both
// drove the allocator to a 64-VGPR target and 10.9 GB of scratch spill.
// Stages at loop index t:
//   P1: Mv update + read partial (step t)                 [t < S]
//   P2: h0 completes read(t-1) -> rfull[(t-1)&1]          [1<=t<=S]
//   P3: z partials for step t-2 (reads rfull[t&1])        [2<=t<=S+1]
//   P4: tanh summary for step t-3 (tid<128)               [3<=t<=S+2]
//   P5: reduce + store outputs step t-4 (wave 4)          [4<=t<=S+3]
// ---------------------------------------------------------------------------
__global__ __launch_bounds__(512)
void rec_kernel(
    const int* __restrict__ q_data, const int* __restrict__ qa_data,
    const float* __restrict__ Mv0,
    const float* __restrict__ Wsm, const float* __restrict__ Sq,
    const float* __restrict__ dqv, const float* __restrict__ EA,
    const unsigned int* __restrict__ WsrP, const float* __restrict__ bs,
    const float* __restrict__ Wab, const float* __restrict__ bab,
    float* __restrict__ out)
{
    const int b = blockIdx.x;
    const int tid = threadIdx.x;
    const int hu = __builtin_amdgcn_readfirstlane(tid >> 8);  // wave-uniform 0..1
    const int g = __builtin_amdgcn_readfirstlane(tid >> 6);   // wave-uniform 0..7
    const int d = tid & 255;       // memory column
    const int l = tid & 63;        // j-pair index for P3
    const bool is_h0 = (tid < 256);

    __shared__ __align__(16) float rbuf1[2][256];
    __shared__ __align__(16) float rfull[2][256];
    __shared__ __align__(16) float zpart[2][8][128];
    __shared__ float sred[2][128];
    __shared__ float dqring[8];

    // Wsr slice -> 32 bf16-packed VGPRs: wsb[kk] = Wsr pair at k=g*32+kk, j=2l,2l+1
    unsigned int wsb[32];
#pragma unroll
    for (int kk = 0; kk < 32; ++kk)
        wsb[kk] = WsrP[(g * 32 + kk) * 64 + l];

    // Mv -> register pairs
    v2f Mv2[32];
#pragma unroll
    for (int k = 0; k < 32; ++k) {
        Mv2[k].x = Mv0[(hu * 64 + 2 * k) * 256 + d];
        Mv2[k].y = Mv0[(hu * 64 + 2 * k + 1) * 256 + d];
    }

    const float bs_j = bs[tid & 127];
    const float wab_j = Wab[tid & 127];
    const float bab_v = bab[0];
    const int* qrow = q_data + b * S_;
    const int* qarow = qa_data + b * S_;

    // scalar id chains (block-uniform)
    int q_c = qrow[0];
    int q_n = qrow[1];
    int qa_n = qarow[1];

    // prologue: row-0 data
    v2f ea = *reinterpret_cast<const v2f*>(&EA[((size_t)qarow[0] * 256 + d) * 2]);
    float sqA = 0.f, sqB = 0.f, sqC = 0.f, sqD = 0.f;
    if (tid < 128) sqA = Sq[q_c * 128 + tid];
    if (tid == 0) dqring[0] = dqv[q_c];
    float rp = 0.f, rp_sv = 0.f;
    __syncthreads();

    for (int t = 0; t <= S_ + 3; ++t) {
        const int s0 = t & 1, s1 = s0 ^ 1;

        // scalar t+2 ids
        int q_nn = 0, qa_nn = 0;
        if (t + 2 < S_) { q_nn = qrow[t + 2]; qa_nn = qarow[t + 2]; }

        // vector prefetch of row t+1 into registers
        const bool hp = (t + 1 < S_);
        v2f pea = { 0.f, 0.f };
        float psq = 0.f, pdq = 0.f;
        if (hp) {
            pea = *reinterpret_cast<const v2f*>(&EA[((size_t)qa_n * 256 + d) * 2]);
            if (tid < 128) psq = Sq[q_n * 128 + tid];
            if (tid == 0) pdq = dqv[q_n];
        }

        // ---- P1: Mv update + read partial (step t); w via scalar loads ----
        if (t < S_) {
            const int qs = __builtin_amdgcn_readfirstlane(q_c);
            const float* __restrict__ wp = Wsm + ((size_t)qs << 7) + (hu << 6);
            const v2f ne2 = { -ea.x, -ea.x };
            const v2f a2 = { ea.y, ea.y };
            v2f rd0 = { 0.f, 0.f }, rd1 = { 0.f, 0.f };
#pragma unroll
            for (int i4 = 0; i4 < 16; ++i4) {
                float4 w4 = *reinterpret_cast<const float4*>(&wp[4 * i4]); // s_load
                v2f wA = { w4.x, w4.y };
                v2f wB = { w4.z, w4.w };
                v2f m0 = Mv2[2 * i4];
                v2f m1 = Mv2[2 * i4 + 1];
                v2f t0 = pkfma(ne2, m0, a2);         // a - e*m
                v2f t1 = pkfma(ne2, m1, a2);
                rd0 = pkfma(wA, m0, rd0);            // read += w*m (old)
                rd1 = pkfma(wB, m1, rd1);
                Mv2[2 * i4]     = pkfma(wA, t0, m0); // m' = m + w*(a-e*m)
                Mv2[2 * i4 + 1] = pkfma(wB, t1, m1);
            }
            v2f rs = rd0 + rd1;
            rp = rs.x + rs.y;
            if (!is_h0) rbuf1[s0][d] = rp;
        }

        // ---- P2: h0 completes read(t-1) ----
        if (is_h0 && t >= 1 && t <= S_) {
            rfull[s1][d] = rp_sv + rbuf1[s1][d];
        }

        // ---- P3: z partials for step t-2 (Wsr from VGPRs) ----
        if (t >= 2 && t <= S_ + 1) {
            const float4* rfp = reinterpret_cast<const float4*>(&rfull[s0][g << 5]);
            v2f acc = { 0.f, 0.f };
#pragma unroll
            for (int k4 = 0; k4 < 8; ++k4) {
                float4 r4 = rfp[k4];                 // broadcast ds_read_b128
#pragma unroll
                for (int u = 0; u < 4; ++u) {
                    unsigned int wv = wsb[k4 * 4 + u];
                    v2f w2 = { __uint_as_float(wv << 16),
                               __uint_as_float(wv & 0xFFFF0000u) };
                    float rr = (u == 0) ? r4.x : (u == 1) ? r4.y : (u == 2) ? r4.z : r4.w;
                    v2f r2 = { rr, rr };
                    acc = pkfma(r2, w2, acc);
                }
            }
            *reinterpret_cast<v2f*>(&zpart[s0][g][2 * l]) = acc;
        }

        // ---- P4: tanh summary for step t-3 (tid<128) ----
        if (tid < 128 && t >= 3 && t <= S_ + 2) {
            float z = ((zpart[s1][0][tid] + zpart[s1][1][tid])
                     + (zpart[s1][2][tid] + zpart[s1][3][tid]))
                    + ((zpart[s1][4][tid] + zpart[s1][5][tid])
                     + (zpart[s1][6][tid] + zpart[s1][7][tid]))
                    + sqD + bs_j;
            float zc = fminf(fmaxf(z, -15.f), 15.f);
            float ex = __expf(2.f * zc);
            sred[s0][tid] = ((ex - 1.f) / (ex + 1.f)) * wab_j;
        }

        // ---- P5: reduce + store outputs for step t-4 (wave 4) ----
        if (t >= 4 && tid >= 256 && tid < 320) {
            int u = tid - 256;
            float v = sred[s1][u] + sred[s1][u + 64];
            v += __shfl_xor(v, 32);
            v += __shfl_xor(v, 16);
            v += __shfl_xor(v, 8);
            v += __shfl_xor(v, 4);
            v += __shfl_xor(v, 2);
            v += __shfl_xor(v, 1);
            if (u == 0) {
                int to = t - 4;
                float ability = v + bab_v;
                float diff = dqring[to & 7];
                out[b * S_ + to] = 3.f * ability - diff;
                out[BS_ + b * S_ + to] = ability;
                out[2 * BS_ + b * S_ + to] = diff;
            }
        }

        // ---- register pipeline shifts + prefetch-write ----
        rp_sv = rp;
        sqD = sqC; sqC = sqB; sqB = sqA; sqA = psq;
        if (hp) {
            ea = pea;
            if (tid == 0) dqring[(t + 1) & 7] = pdq;
        }
        q_c = q_n; q_n = q_nn; qa_n = qa_nn;

        __syncthreads();
    }
}

// ---------------------------------------------------------------------------
extern "C" void kernel_launch(void* const* d_in, const int* in_sizes, int n_in,
                              void* d_out, int out_size, void* d_ws, size_t ws_size,
                              hipStream_t stream) {
    const int* q_data  = (const int*)d_in[0];
    const int* qa_data = (const int*)d_in[1];
    const float* Mk       = (const float*)d_in[3];
    const float* Mv0      = (const float*)d_in[4];
    const float* q_embed  = (const float*)d_in[5];
    const float* qa_embed = (const float*)d_in[6];
    const float* We  = (const float*)d_in[7];
    const float* be  = (const float*)d_in[8];
    const float* Wa  = (const float*)d_in[9];
    const float* ba  = (const float*)d_in[10];
    const float* Ws  = (const float*)d_in[11];
    const float* bs  = (const float*)d_in[12];
    const float* Wab = (const float*)d_in[13];
    const float* bab = (const float*)d_in[14];
    const float* Wd  = (const float*)d_in[15];
    const float* bd  = (const float*)d_in[16];
    float* out = (float*)d_out;

    float* ws   = (float*)d_ws;
    float* WeT  = ws;                       // 65536
    float* WaT  = WeT  + 65536;             // 65536
    float* MkT  = WaT  + 65536;             // 16384
    float* WsqT = MkT  + 16384;             // 16384
    unsigned int* WsrP = (unsigned int*)(WsqT + 16384);  // 16384 u32
    float* Wsm  = (float*)(WsrP + 16384);   // NQ1_*128
    float* Sq   = Wsm  + NQ1_ * 128;        // NQ1_*128
    float* dqv  = Sq   + NQ1_ * 128;        // 10016
    float* EA   = dqv  + 10016;             // NQA1_*512 (float2 interleaved)
    // total ≈ 52 MB (same footprint as the passing round-2)

    prep_kernel<<<704, 256, 0, stream>>>(We, Wa, Mk, Ws, WeT, WaT, MkT, WsqT, WsrP);
    kq_kernel<<<(NQ1_ + 7) / 8, 64, 0, stream>>>(q_embed, MkT, WsqT, Wd, bd, Wsm, Sq, dqv);
    kqa_kernel<<<(NQA1_ + 7) / 8, 128, 0, stream>>>(qa_embed, WeT, WaT, be, ba, EA);
    rec_kernel<<<B_, 512, 0, stream>>>(q_data, qa_data, Mv0, Wsm, Sq, dqv, EA,
                                       WsrP, bs, Wab, bab, out);
}

// Round 9
// 1317.610 us; speedup vs baseline: 1.4221x; 1.4221x over previous
//
#include <hip/hip_runtime.h>
#include <math.h>

#define B_ 512
#define S_ 500
#define NQ1_ 10001
#define NQA1_ 20001
#define BS_ (B_ * S_)

typedef float v2f __attribute__((ext_vector_type(2)));
static __device__ __forceinline__ v2f pkfma(v2f a, v2f b, v2f c) {
    return __builtin_elementwise_fma(a, b, c);
}

// ---------------------------------------------------------------------------
// Fused prep: WeT, WaT, MkT, WsqT transposes + WsrB4 bf16-pack.
// WsrB4[(d4*64 + j2)*4 + s] = bf16(Ws[2*j2][d]) | bf16(Ws[2*j2+1][d])<<16,
// with d = d4*4+s (d<256 read-columns of Ws, j2<64 j-pairs).
// ---------------------------------------------------------------------------
__global__ __launch_bounds__(256) void prep_kernel(
    const float* __restrict__ We, const float* __restrict__ Wa,
    const float* __restrict__ Mk, const float* __restrict__ Ws,
    float* __restrict__ WeT, float* __restrict__ WaT,
    float* __restrict__ MkT, float* __restrict__ WsqT,
    unsigned int* __restrict__ WsrB4)
{
    int idx = blockIdx.x * 256 + threadIdx.x;
    if (idx < 65536) {
        int r = idx >> 8, c = idx & 255;
        WeT[c * 256 + r] = We[r * 256 + c];
        return;
    }
    idx -= 65536;
    if (idx < 65536) {
        int r = idx >> 8, c = idx & 255;
        WaT[c * 256 + r] = Wa[r * 256 + c];
        return;
    }
    idx -= 65536;
    if (idx < 16384) {
        int r = idx >> 7, c = idx & 127;
        MkT[c * 128 + r] = Mk[r * 128 + c];
        return;
    }
    idx -= 16384;
    if (idx < 16384) {
        int r = idx >> 7, c = idx & 127;
        WsqT[c * 128 + r] = Ws[r * 384 + 256 + c];
        return;
    }
    idx -= 16384;
    if (idx < 16384) {
        int j2 = (idx >> 2) & 63;
        int s = idx & 3;
        int dd = (idx >> 8) * 4 + s;
        unsigned int b0 = __float_as_uint(Ws[(2 * j2) * 384 + dd]);
        unsigned int b1 = __float_as_uint(Ws[(2 * j2 + 1) * 384 + dd]);
        WsrB4[idx] = ((b0 + 0x8000u) >> 16) | ((b1 + 0x8000u) & 0xFFFF0000u);
    }
}

// ---------------------------------------------------------------------------
// Per-q-index precompute: Wsm = softmax(q@Mk.T), Sq = q@Ws_q.T, dq = tanh(q@Wd+bd)
// ---------------------------------------------------------------------------
__global__ __launch_bounds__(64) void kq_kernel(
    const float* __restrict__ q_embed, const float* __restrict__ MkT,
    const float* __restrict__ WsqT, const float* __restrict__ Wd,
    const float* __restrict__ bdp,
    float* __restrict__ Wsm, float* __restrict__ Sq, float* __restrict__ dqv)
{
    int i0 = blockIdx.x * 8;
    int l = threadIdx.x;  // 0..63 -> j = 2l, 2l+1
    __shared__ float qlds[8][128];

#pragma unroll
    for (int r = 0; r < 8; ++r) {
        int i = i0 + r;
        v2f qv = { 0.f, 0.f };
        if (i < NQ1_) qv = *reinterpret_cast<const v2f*>(&q_embed[i * 128 + 2 * l]);
        *reinterpret_cast<v2f*>(&qlds[r][2 * l]) = qv;
    }
    __syncthreads();

    v2f lg[8], sq[8];
#pragma unroll
    for (int r = 0; r < 8; ++r) { lg[r] = (v2f){0.f, 0.f}; sq[r] = (v2f){0.f, 0.f}; }

    for (int k = 0; k < 128; ++k) {
        v2f mk = *reinterpret_cast<const v2f*>(&MkT[k * 128 + 2 * l]);
        v2f wq = *reinterpret_cast<const v2f*>(&WsqT[k * 128 + 2 * l]);
#pragma unroll
        for (int r = 0; r < 8; ++r) {
            float q = qlds[r][k];
            v2f q2 = { q, q };
            lg[r] = pkfma(q2, mk, lg[r]);
            sq[r] = pkfma(q2, wq, sq[r]);
        }
    }

    v2f wd2 = *reinterpret_cast<const v2f*>(&Wd[2 * l]);
    float bd = bdp[0];

#pragma unroll
    for (int r = 0; r < 8; ++r) {
        int i = i0 + r;
        float m = fmaxf(lg[r].x, lg[r].y);
        for (int off = 32; off; off >>= 1) m = fmaxf(m, __shfl_xor(m, off));
        float ex0 = expf(lg[r].x - m), ex1 = expf(lg[r].y - m);
        float s = ex0 + ex1;
        for (int off = 32; off; off >>= 1) s += __shfl_xor(s, off);
        float inv = 1.f / s;
        if (i < NQ1_) {
            v2f o = { ex0 * inv, ex1 * inv };
            *reinterpret_cast<v2f*>(&Wsm[i * 128 + 2 * l]) = o;
            *reinterpret_cast<v2f*>(&Sq[i * 128 + 2 * l]) = sq[r];
        }
        float dd = qlds[r][2 * l] * wd2.x + qlds[r][2 * l + 1] * wd2.y;
        for (int off = 32; off; off >>= 1) dd += __shfl_xor(dd, off);
        if (l == 0 && i < NQ1_) dqv[i] = tanhf(dd + bd);
    }
}

// ---------------------------------------------------------------------------
// Per-qa-index precompute: EA[i][d] = (sigmoid(..)_d, tanh(..)_d) interleaved.
// ---------------------------------------------------------------------------
__global__ __launch_bounds__(128) void kqa_kernel(
    const float* __restrict__ qa_embed, const float* __restrict__ WeT,
    const float* __restrict__ WaT, const float* __restrict__ be,
    const float* __restrict__ ba, float* __restrict__ EA)
{
    int i0 = blockIdx.x * 8;
    int l = threadIdx.x;  // 0..127 -> d = 2l, 2l+1
    __shared__ float qlds[8][256];

#pragma unroll
    for (int r = 0; r < 8; ++r) {
        int i = i0 + r;
        v2f qv = { 0.f, 0.f };
        if (i < NQA1_) qv = *reinterpret_cast<const v2f*>(&qa_embed[i * 256 + 2 * l]);
        *reinterpret_cast<v2f*>(&qlds[r][2 * l]) = qv;
    }
    __syncthreads();

    v2f be2 = *reinterpret_cast<const v2f*>(&be[2 * l]);
    v2f ba2 = *reinterpret_cast<const v2f*>(&ba[2 * l]);
    v2f zE[8], zA[8];
#pragma unroll
    for (int r = 0; r < 8; ++r) { zE[r] = be2; zA[r] = ba2; }

    for (int k = 0; k < 256; ++k) {
        v2f we2 = *reinterpret_cast<const v2f*>(&WeT[k * 256 + 2 * l]);
        v2f wa2 = *reinterpret_cast<const v2f*>(&WaT[k * 256 + 2 * l]);
#pragma unroll
        for (int r = 0; r < 8; ++r) {
            float q = qlds[r][k];
            v2f q2 = { q, q };
            zE[r] = pkfma(q2, we2, zE[r]);
            zA[r] = pkfma(q2, wa2, zA[r]);
        }
    }
#pragma unroll
    for (int r = 0; r < 8; ++r) {
        int i = i0 + r;
        if (i < NQA1_) {
            float4 o;
            o.x = 1.f / (1.f + expf(-zE[r].x));
            o.y = tanhf(zA[r].x);
            o.z = 1.f / (1.f + expf(-zE[r].y));
            o.w = tanhf(zA[r].y);
            *reinterpret_cast<float4*>(&EA[(size_t)(i * 256 + 2 * l) * 2]) = o;
        }
    }
}

// ---------------------------------------------------------------------------
// Recurrence v4: BARRIER-FREE steps, one barrier per 16-step epoch (32 total).
//  - 256 threads/block; thread d owns the FULL Mv column: 128 f32 = 64 v2f
//    VGPRs. read[d] = sum_m w[m]*Mv[m][d] is thread-local -> no per-step
//    cross-thread reduction, no per-step barrier, no vmcnt(0) drains.
//  - w rows: per-epoch LDS double buffer (16 rows, broadcast b128 reads),
//    reg-staged during the previous epoch.
//  - EA: depth-4 per-thread register prefetch ring (unroll-4 -> static idx);
//    qa-id ring likewise (ids are uniform -> SGPRs).
//  - read rows -> LDS ring rbuf[2][256][18] (pad 18 vs 16: write conflicts).
//  - z-phase per epoch after the single barrier: z[t][j] for 16 t x 128 j,
//    Wsr streamed bf16-packed uint4 from global (64KB, L2-hot, coalesced);
//    rbuf read as uniform broadcasts; wave wv owns t = e*16+wv*4+c;
//    64-lane shuffle reduce; lane 0 stores pred/ability/diff.
//  - T=512 padded (ids clamped to 499; stores guarded t<500).
// Plain __launch_bounds__(256): (512,4)/waves_per_eu(4) caused 64-reg spill
// catastrophes in rounds 4-6; plain bounds allocated cleanly in 2/7/8.
// ---------------------------------------------------------------------------
__global__ __launch_bounds__(256)
void rec_kernel(
    const int* __restrict__ q_data, const int* __restrict__ qa_data,
    const float* __restrict__ Mv0,
    const float* __restrict__ Wsm, const float* __restrict__ Sq,
    const float* __restrict__ dqv, const float* __restrict__ EA,
    const unsigned int* __restrict__ WsrB4, const float* __restrict__ bs,
    const float* __restrict__ Wab, const float* __restrict__ bab,
    float* __restrict__ out)
{
    const int b = blockIdx.x;
    const int tid = threadIdx.x;
    const int d = tid;             // memory column owned by this thread
    const int wv = tid >> 6;       // wave 0..3
    const int l = tid & 63;        // lane; j-pair index in z-phase

    __shared__ __align__(16) float wbuf[2][16][128];
    __shared__ __align__(16) float rbuf[2][256][18];

    const int* qrow = q_data + b * S_;
    const int* qarow = qa_data + b * S_;

    // Mv full column in registers
    v2f Mv2[64];
#pragma unroll
    for (int m = 0; m < 64; ++m) {
        Mv2[m].x = Mv0[(2 * m) * 256 + d];
        Mv2[m].y = Mv0[(2 * m + 1) * 256 + d];
    }

    v2f bs2 = *reinterpret_cast<const v2f*>(&bs[2 * l]);
    v2f wab2 = *reinterpret_cast<const v2f*>(&Wab[2 * l]);
    const float babv = bab[0];

    const int r_s = tid >> 4;      // staging: row 0..15
    const int c_s = tid & 15;      // staging: 8-float chunk 0..15

    // prologue: stage epoch-0 w rows directly
    {
        int qid = qrow[r_s];
        const float* wsrc = Wsm + (size_t)qid * 128 + c_s * 8;
        *reinterpret_cast<float4*>(&wbuf[0][r_s][c_s * 8]) =
            *reinterpret_cast<const float4*>(wsrc);
        *reinterpret_cast<float4*>(&wbuf[0][r_s][c_s * 8 + 4]) =
            *reinterpret_cast<const float4*>(wsrc + 4);
    }
    // ring warmup: ear[u] = EA for t=u; idr[u] = qa id for t=u+4
    v2f ear[4];
    int idr[4];
#pragma unroll
    for (int u = 0; u < 4; ++u) {
        ear[u] = *reinterpret_cast<const v2f*>(&EA[((size_t)qarow[u] * 256 + d) * 2]);
        idr[u] = qarow[4 + u];
    }
    __syncthreads();

    for (int e = 0; e < 32; ++e) {
        const int eb = e & 1;

        // ---- stage issue: w rows for epoch e+1 (written to LDS pre-barrier) ----
        int t1 = (e + 1) * 16 + r_s; if (t1 > 499) t1 = 499;
        const float* wsrc = Wsm + (size_t)qrow[t1] * 128 + c_s * 8;
        float4 sw0 = *reinterpret_cast<const float4*>(wsrc);
        float4 sw1 = *reinterpret_cast<const float4*>(wsrc + 4);

        // ---- 16 barrier-free steps ----
        for (int kg = 0; kg < 4; ++kg) {
#pragma unroll
            for (int u = 0; u < 4; ++u) {
                const int k = kg * 4 + u;
                const int t = e * 16 + k;
                const float e_d = ear[u].x;
                const float a_d = ear[u].y;
                // refill rings (ea for t+4, qa-id for t+8)
                {
                    int qa4 = idr[u];
                    ear[u] = *reinterpret_cast<const v2f*>(
                        &EA[((size_t)qa4 * 256 + d) * 2]);
                    int t8 = t + 8; if (t8 > 499) t8 = 499;
                    idr[u] = qarow[t8];
                }
                const v2f ne2 = { -e_d, -e_d };
                const v2f a2 = { a_d, a_d };
                v2f rd0 = { 0.f, 0.f }, rd1 = { 0.f, 0.f };
                const float4* wp = reinterpret_cast<const float4*>(&wbuf[eb][k][0]);
#pragma unroll
                for (int mq = 0; mq < 32; ++mq) {
                    float4 w4 = wp[mq];                   // uniform broadcast b128
                    v2f wA = { w4.x, w4.y };
                    v2f wB = { w4.z, w4.w };
                    v2f mA = Mv2[2 * mq];
                    v2f mB = Mv2[2 * mq + 1];
                    v2f tA = pkfma(ne2, mA, a2);          // a - e*m
                    v2f tB = pkfma(ne2, mB, a2);
                    rd0 = pkfma(wA, mA, rd0);             // read += w*m (old)
                    rd1 = pkfma(wB, mB, rd1);
                    Mv2[2 * mq]     = pkfma(wA, tA, mA);  // m' = m + w*(a-e*m)
                    Mv2[2 * mq + 1] = pkfma(wB, tB, mB);
                }
                v2f rs = rd0 + rd1;
                rbuf[eb][d][k] = rs.x + rs.y;
            }
        }

        // ---- z-phase inputs for this epoch (wave wv owns t=e*16+wv*4+c) ----
        v2f sqv[4];
        float dqvv[4];
#pragma unroll
        for (int c = 0; c < 4; ++c) {
            int tt = e * 16 + wv * 4 + c; if (tt > 499) tt = 499;
            int qtc = qrow[tt];
            sqv[c] = *reinterpret_cast<const v2f*>(&Sq[(size_t)qtc * 128 + 2 * l]);
            dqvv[c] = dqv[qtc];
        }

        // ---- stage write + the ONE barrier of this epoch ----
        *reinterpret_cast<float4*>(&wbuf[eb ^ 1][r_s][c_s * 8]) = sw0;
        *reinterpret_cast<float4*>(&wbuf[eb ^ 1][r_s][c_s * 8 + 4]) = sw1;
        __syncthreads();

        // ---- z-phase: z[t][2l,2l+1] = sum_d rbuf[d][t] * Wsr  (bf16 global) ----
        v2f acc0 = { 0.f, 0.f }, acc1 = { 0.f, 0.f };
        v2f acc2 = { 0.f, 0.f }, acc3 = { 0.f, 0.f };
        const uint4* wrp = reinterpret_cast<const uint4*>(WsrB4) + l;
#pragma unroll 4
        for (int d4 = 0; d4 < 64; ++d4) {
            uint4 wq = wrp[(size_t)d4 * 64];              // coalesced, L2-hot
#pragma unroll
            for (int s = 0; s < 4; ++s) {
                int dd = d4 * 4 + s;
                v2f rA = *reinterpret_cast<const v2f*>(&rbuf[eb][dd][wv * 4]);
                v2f rB = *reinterpret_cast<const v2f*>(&rbuf[eb][dd][wv * 4 + 2]);
                unsigned int wvv = (s == 0) ? wq.x : (s == 1) ? wq.y
                                 : (s == 2) ? wq.z : wq.w;
                v2f w2 = { __uint_as_float(wvv << 16),
                           __uint_as_float(wvv & 0xFFFF0000u) };
                v2f ra = { rA.x, rA.x }; acc0 = pkfma(ra, w2, acc0);
                v2f rb = { rA.y, rA.y }; acc1 = pkfma(rb, w2, acc1);
                v2f rc = { rB.x, rB.x }; acc2 = pkfma(rc, w2, acc2);
                v2f rdv = { rB.y, rB.y }; acc3 = pkfma(rdv, w2, acc3);
            }
        }
        v2f accs[4] = { acc0, acc1, acc2, acc3 };
#pragma unroll
        for (int c = 0; c < 4; ++c) {
            v2f z2 = accs[c] + sqv[c] + bs2;
            float zx = fminf(fmaxf(z2.x, -15.f), 15.f);
            float zy = fminf(fmaxf(z2.y, -15.f), 15.f);
            float ex = __expf(2.f * zx);
            float ey = __expf(2.f * zy);
            float sv = ((ex - 1.f) / (ex + 1.f)) * wab2.x
                     + ((ey - 1.f) / (ey + 1.f)) * wab2.y;
            sv += __shfl_xor(sv, 32);
            sv += __shfl_xor(sv, 16);
            sv += __shfl_xor(sv, 8);
            sv += __shfl_xor(sv, 4);
            sv += __shfl_xor(sv, 2);
            sv += __shfl_xor(sv, 1);
            if (l == 0) {
                int tt = e * 16 + wv * 4 + c;
                if (tt < 500) {
                    float ab = sv + babv;
                    float dq = dqvv[c];
                    out[b * S_ + tt] = 3.f * ab - dq;
                    out[BS_ + b * S_ + tt] = ab;
                    out[2 * BS_ + b * S_ + tt] = dq;
                }
            }
        }
    }
}

// ---------------------------------------------------------------------------
extern "C" void kernel_launch(void* const* d_in, const int* in_sizes, int n_in,
                              void* d_out, int out_size, void* d_ws, size_t ws_size,
                              hipStream_t stream) {
    const int* q_data  = (const int*)d_in[0];
    const int* qa_data = (const int*)d_in[1];
    const float* Mk       = (const float*)d_in[3];
    const float* Mv0      = (const float*)d_in[4];
    const float* q_embed  = (const float*)d_in[5];
    const float* qa_embed = (const float*)d_in[6];
    const float* We  = (const float*)d_in[7];
    const float* be  = (const float*)d_in[8];
    const float* Wa  = (const float*)d_in[9];
    const float* ba  = (const float*)d_in[10];
    const float* Ws  = (const float*)d_in[11];
    const float* bs  = (const float*)d_in[12];
    const float* Wab = (const float*)d_in[13];
    const float* bab = (const float*)d_in[14];
    const float* Wd  = (const float*)d_in[15];
    const float* bd  = (const float*)d_in[16];
    float* out = (float*)d_out;

    float* ws   = (float*)d_ws;
    float* WeT  = ws;                       // 65536
    float* WaT  = WeT  + 65536;             // 65536
    float* MkT  = WaT  + 65536;             // 16384
    float* WsqT = MkT  + 16384;             // 16384
    unsigned int* WsrB4 = (unsigned int*)(WsqT + 16384);  // 16384 u32
    float* Wsm  = (float*)(WsrB4 + 16384);  // NQ1_*128
    float* Sq   = Wsm  + NQ1_ * 128;        // NQ1_*128
    float* dqv  = Sq   + NQ1_ * 128;        // 10016
    float* EA   = dqv  + 10016;             // NQA1_*512 (float2 interleaved)
    // total ~= 52 MB (identical footprint to the passing rounds)

    prep_kernel<<<704, 256, 0, stream>>>(We, Wa, Mk, Ws, WeT, WaT, MkT, WsqT, WsrB4);
    kq_kernel<<<(NQ1_ + 7) / 8, 64, 0, stream>>>(q_embed, MkT, WsqT, Wd, bd, Wsm, Sq, dqv);
    kqa_kernel<<<(NQA1_ + 7) / 8, 128, 0, stream>>>(qa_embed, WeT, WaT, be, ba, EA);
    rec_kernel<<<B_, 256, 0, stream>>>(q_data, qa_data, Mv0, Wsm, Sq, dqv, EA,
                                       WsrB4, bs, Wab, bab, out);
}